// Round 7
// baseline (202.819 us; speedup 1.0000x reference)
//
#include <hip/hip_runtime.h>
#include <math.h>

#define B_ 64
#define T_ 256
#define K_ 128

typedef const __attribute__((address_space(1))) void* gas1_t;
typedef __attribute__((address_space(3))) void* las3_t;
typedef float f32x4 __attribute__((ext_vector_type(4)));
typedef short bf16x8 __attribute__((ext_vector_type(8)));

static __device__ __forceinline__ unsigned int bf16rne(float x) {
    unsigned int u = __builtin_bit_cast(unsigned int, x);
    return (u + 0x7FFFu + ((u >> 16) & 1u)) >> 16;
}
static __device__ __forceinline__ unsigned int pkbf16(float a, float b) {
    return bf16rne(a) | (bf16rne(b) << 16);
}
// round-half-up bf16x2 pack: cheap, ~unbiased
static __device__ __forceinline__ unsigned int pkrhu(float a, float b) {
    unsigned int ua = __builtin_bit_cast(unsigned int, a);
    unsigned int ub = __builtin_bit_cast(unsigned int, b);
    return ((ua + 0x8000u) >> 16) | ((ub + 0x8000u) & 0xFFFF0000u);
}

// One wave per batch. MFMA matvec with register-closed recurrence:
//   A-frags hold E rows permuted by sigma(rt,m) = 32(rt>>1)+8(m>>2)+4(rt&1)+(m&3)
//   B-frags hold v[32kt+8g+j] replicated over ci (B[k][n] identical per column)
//   => lane (g,ci) accs hold u at exactly the global rows {32kt+8g+j} it needs
//      to rebuild the next B-frag locally. Zero LDS/shuffle/barrier per step.
__global__ __launch_bounds__(64) void crf_fwd_kernel(
    const float* __restrict__ y,
    const float* __restrict__ mask,
    const float* __restrict__ trans,
    float* __restrict__ out)
{
    const int b    = blockIdx.x;
    const int lane = threadIdx.x;   // 0..63
    const int g    = lane >> 4;     // 0..3
    const int ci   = lane & 15;     // replication index (and A-row selector)

    __shared__ __align__(16) float ybuf[2][32 * K_];   // 2 x 16 KB y chunks

    const float* yb = y + (size_t)b * (T_ * K_);
    auto stage = [&](int c, int buf) {
        const float* gp = yb + (size_t)c * (32 * K_);
        #pragma unroll
        for (int s = 0; s < 16; ++s)
            __builtin_amdgcn_global_load_lds(
                (gas1_t)(gp + s * 256 + lane * 4),
                (las3_t)(&ybuf[buf][s * 256]), 16, 0, 0);
    };

    stage(0, 0);   // overlaps L/E setup

    // ---- sequence length (mask contiguous 1.0/0.0) ----
    float4 mv = *(const float4*)(mask + b * T_ + (lane << 2));
    float lc = (mv.x + mv.y) + (mv.z + mv.w);
    lc += __shfl_xor(lc, 1);
    lc += __shfl_xor(lc, 2);
    lc += __shfl_xor(lc, 4);
    lc += __shfl_xor(lc, 8);
    lc += __shfl_xor(lc, 16);
    lc += __shfl_xor(lc, 32);
    const int L = (int)lc;                // in [128, 256]
    const int nch = (L + 31) >> 5;        // 4..8 chunks

    // ---- A-frags: E = exp(trans), rows permuted by sigma ----
    bf16x8 A[8][4];
    #pragma unroll
    for (int rt = 0; rt < 8; ++rt) {
        const int R = 32 * (rt >> 1) + 8 * (ci >> 2) + 4 * (rt & 1) + (ci & 3);
        const float* tp = trans + R * K_;
        #pragma unroll
        for (int kt = 0; kt < 4; ++kt) {
            f32x4 p = *(const f32x4*)(tp + 32 * kt + 8 * g);
            f32x4 q = *(const f32x4*)(tp + 32 * kt + 8 * g + 4);
            uint4 u = make_uint4(pkbf16(__expf(p.x), __expf(p.y)),
                                 pkbf16(__expf(p.z), __expf(p.w)),
                                 pkbf16(__expf(q.x), __expf(q.y)),
                                 pkbf16(__expf(q.z), __expf(q.w)));
            A[rt][kt] = __builtin_bit_cast(bf16x8, u);
        }
    }

    // ---- v = one-hot SOS (state 2): kt=0, g=0, dword1 low half ----
    uint4 Bw[4];
    #pragma unroll
    for (int kt = 0; kt < 4; ++kt) Bw[kt] = make_uint4(0u, 0u, 0u, 0u);
    if (g == 0) Bw[0].y = 0x3F80u;

    float c_acc = 0.0f;
    f32x4 w[8];
    #pragma unroll
    for (int rt = 0; rt < 8; ++rt) w[rt] = f32x4{0.f, 0.f, 0.f, 0.f};

    for (int c = 0; c < nch; ++c) {
        if (c + 1 < nch) {
            stage(c + 1, (c + 1) & 1);     // prefetch next chunk first...
            asm volatile("s_waitcnt vmcnt(16)" ::: "memory");   // ...then wait chunk c
        } else {
            asm volatile("s_waitcnt vmcnt(0)" ::: "memory");
        }
        float* bp = ybuf[c & 1];

        // per-chunk exp pass: y -> exp(y) in LDS (hoists 32 exps/step out of the loop)
        #pragma unroll
        for (int i = 0; i < 16; ++i) {
            f32x4 v4 = *(const f32x4*)(bp + i * 256 + (lane << 2));
            v4.x = __expf(v4.x); v4.y = __expf(v4.y);
            v4.z = __expf(v4.z); v4.w = __expf(v4.w);
            *(f32x4*)(bp + i * 256 + (lane << 2)) = v4;
        }

        const int rem = L - 32 * c;
        const int ns  = rem < 32 ? rem : 32;
        for (int tt = 0; tt < ns; ++tt) {
            const float* yt = bp + tt * K_;

            // ey at this lane's output rows: base 32(rt>>1)+8g+4(rt&1)
            f32x4 ey[8];
            #pragma unroll
            for (int rt = 0; rt < 8; ++rt) {
                const int rho = 32 * (rt >> 1) + 8 * g + 4 * (rt & 1);
                ey[rt] = *(const f32x4*)(yt + rho);   // 16-lane broadcast read
            }

            // u = E*v (32 MFMA, 8 independent 4-chains), then w = ey .* u
            #pragma unroll
            for (int rt = 0; rt < 8; ++rt) {
                f32x4 a = {0.f, 0.f, 0.f, 0.f};
                #pragma unroll
                for (int kt = 0; kt < 4; ++kt)
                    a = __builtin_amdgcn_mfma_f32_16x16x32_bf16(
                            A[rt][kt], __builtin_bit_cast(bf16x8, Bw[kt]), a, 0, 0, 0);
                w[rt] = a * ey[rt];
            }

            // renorm every 4 active steps (exact bookkeeping)
            if (((32 * c + tt) & 3) == 3) {
                f32x4 sv = w[0];
                #pragma unroll
                for (int rt = 1; rt < 8; ++rt) sv += w[rt];
                float S = (sv.x + sv.y) + (sv.z + sv.w);   // lane's 32 disjoint rows
                S += __shfl_xor(S, 16);                    // combine over g
                S += __shfl_xor(S, 32);
                float rinv = __builtin_amdgcn_rcpf(S);
                c_acc += __logf(S);
                #pragma unroll
                for (int rt = 0; rt < 8; ++rt) w[rt] *= rinv;
            }

            // rebuild next B-frag from OWN registers (sigma closes the loop):
            // Bw[kt] dwords = rows {32kt+8g+0..7} = w[2kt].xyzw, w[2kt+1].xyzw
            #pragma unroll
            for (int kt = 0; kt < 4; ++kt) {
                const f32x4 s0 = w[2 * kt], s1 = w[2 * kt + 1];
                Bw[kt] = make_uint4(pkrhu(s0.x, s0.y), pkrhu(s0.z, s0.w),
                                    pkrhu(s1.x, s1.y), pkrhu(s1.z, s1.w));
            }
        }
    }

    // out[b] = c_acc + log(sum v)
    f32x4 sv = w[0];
    #pragma unroll
    for (int rt = 1; rt < 8; ++rt) sv += w[rt];
    float S = (sv.x + sv.y) + (sv.z + sv.w);
    S += __shfl_xor(S, 16);
    S += __shfl_xor(S, 32);
    if (lane == 0) out[b] = c_acc + __logf(S);
}

extern "C" void kernel_launch(void* const* d_in, const int* in_sizes, int n_in,
                              void* d_out, int out_size, void* d_ws, size_t ws_size,
                              hipStream_t stream) {
    const float* y     = (const float*)d_in[0];   // (B, T, K) fp32
    const float* mask  = (const float*)d_in[1];   // (B, T)    fp32 0/1
    const float* trans = (const float*)d_in[2];   // (K, K)    fp32
    float* out = (float*)d_out;                    // (B,)      fp32
    crf_fwd_kernel<<<B_, 64, 0, stream>>>(y, mask, trans, out);
}

// Round 8
// 154.804 us; speedup vs baseline: 1.3102x; 1.3102x over previous
//
#include <hip/hip_runtime.h>
#include <math.h>

#define B_ 64
#define T_ 256
#define K_ 128

typedef const __attribute__((address_space(1))) void* gas1_t;
typedef __attribute__((address_space(3))) void* las3_t;
typedef float f32x4 __attribute__((ext_vector_type(4)));
typedef short bf16x8 __attribute__((ext_vector_type(8)));

static __device__ __forceinline__ unsigned int bf16rne(float x) {
    unsigned int u = __builtin_bit_cast(unsigned int, x);
    return (u + 0x7FFFu + ((u >> 16) & 1u)) >> 16;
}
static __device__ __forceinline__ unsigned int pkbf16(float a, float b) {
    return bf16rne(a) | (bf16rne(b) << 16);
}

// One 256-thread block (4 waves) per batch element. Wave w owns output rows
// [32w, 32w+32): 2 M-tiles x 4 K-frags = 8 MFMA/step on its OWN SIMD -> 4x
// less per-SIMD MFMA issue than the one-wave R6 design (MFMA rate is
// per-SIMD: ~19.4 cyc per 16x16x32). v (128 bf16 = 256 B) is exchanged
// through double-buffered LDS; all v reads are 16-lane same-address
// broadcasts (conflict-free), one __syncthreads per step. Renorm every 4
// steps via deferred partial sums (written t%4==3, consumed t%4==0).
__global__ __launch_bounds__(256) void crf_fwd_kernel(
    const float* __restrict__ y,
    const float* __restrict__ mask,
    const float* __restrict__ trans,
    float* __restrict__ out)
{
    const int b    = blockIdx.x;
    const int tid  = threadIdx.x;
    const int w    = tid >> 6;      // wave 0..3 -> rows [32w, 32w+32)
    const int lane = tid & 63;
    const int quad = lane >> 4;     // 0..3
    const int ci   = lane & 15;

    __shared__ __align__(16) float eybuf[2][32 * K_];    // 2 x 16 KB y chunks
    __shared__ __align__(16) unsigned short vS[2][K_];   // v double buffer (bf16)
    __shared__ __align__(16) float wsumS[4];             // deferred renorm partials
    __shared__ __align__(16) float redS[4];
    __shared__ int lenS[4];

    const float* yb = y + (size_t)b * (T_ * K_);
    auto stage = [&](int c, int buf) {                   // 4 global_load_lds per wave
        const float* gp = yb + (size_t)c * (32 * K_);
        #pragma unroll
        for (int s = 0; s < 4; ++s) {
            const int seg = 4 * w + s;                   // 16 segments x 1 KB
            __builtin_amdgcn_global_load_lds(
                (gas1_t)(gp + seg * 256 + lane * 4),
                (las3_t)(&eybuf[buf][seg * 256]), 16, 0, 0);
        }
    };

    stage(0, 0);

    // ---- sequence length (mask contiguous 1.0/0.0) ----
    float mval = mask[b * T_ + tid];
    unsigned long long bal = __ballot(mval != 0.0f);
    if (lane == 0) lenS[w] = __popcll(bal);

    // ---- A-frags: E rows 32w+16mt+ci, A[m=ci][k=8quad+j] per (mt,kt) ----
    bf16x8 A[2][4];
    #pragma unroll
    for (int mt = 0; mt < 2; ++mt) {
        const float* tp = trans + (32 * w + 16 * mt + ci) * K_;
        #pragma unroll
        for (int kt = 0; kt < 4; ++kt) {
            f32x4 p = *(const f32x4*)(tp + 32 * kt + 8 * quad);
            f32x4 q = *(const f32x4*)(tp + 32 * kt + 8 * quad + 4);
            uint4 u = make_uint4(pkbf16(__expf(p.x), __expf(p.y)),
                                 pkbf16(__expf(p.z), __expf(p.w)),
                                 pkbf16(__expf(q.x), __expf(q.y)),
                                 pkbf16(__expf(q.z), __expf(q.w)));
            A[mt][kt] = __builtin_bit_cast(bf16x8, u);
        }
    }

    // ---- v(0) = one-hot SOS (bf16) ----
    if (tid < K_) vS[0][tid] = (tid == 2) ? 0x3F80 : 0;
    __syncthreads();
    const int L = lenS[0] + lenS[1] + lenS[2] + lenS[3];   // in [128, 256]
    const int nch = (L + 31) >> 5;

    float c_acc = 0.0f;
    int cur = 0;
    f32x4 w0 = {0.f, 0.f, 0.f, 0.f}, w1 = {0.f, 0.f, 0.f, 0.f};

    for (int c = 0; c < nch; ++c) {
        if (c + 1 < nch) {
            stage(c + 1, (c + 1) & 1);   // prefetch first (per-wave vmcnt: 4+4)
            asm volatile("s_waitcnt vmcnt(4)" ::: "memory");   // chunk c's 4 done
        } else {
            asm volatile("s_waitcnt vmcnt(0)" ::: "memory");
        }
        __syncthreads();                 // all waves' DMA for chunk c visible
        float* bp = eybuf[c & 1];
        #pragma unroll
        for (int i = 0; i < 4; ++i) {    // pre-exp pass (4096 floats / 256 thr)
            f32x4 v4 = *(const f32x4*)(bp + i * 1024 + tid * 4);
            v4.x = __expf(v4.x); v4.y = __expf(v4.y);
            v4.z = __expf(v4.z); v4.w = __expf(v4.w);
            *(f32x4*)(bp + i * 1024 + tid * 4) = v4;
        }
        __syncthreads();

        const int rem = L - 32 * c;
        const int ns = rem < 32 ? rem : 32;
        for (int tt = 0; tt < ns; ++tt) {
            const int t = 32 * c + tt;

            // B-frags: B[k=8quad+j][n] = v[32kt+8quad+j], same addr for all ci
            const unsigned short* vp = vS[cur];
            bf16x8 Bf[4];
            #pragma unroll
            for (int kt = 0; kt < 4; ++kt)
                Bf[kt] = *(const bf16x8*)&vp[32 * kt + 8 * quad];

            // ey at this lane's output rows (broadcast f32x4)
            const float* yt = bp + tt * K_ + 32 * w + 4 * quad;
            f32x4 ey0 = *(const f32x4*)(yt);
            f32x4 ey1 = *(const f32x4*)(yt + 16);

            f32x4 a0 = {0.f, 0.f, 0.f, 0.f}, a1 = {0.f, 0.f, 0.f, 0.f};
            #pragma unroll
            for (int kt = 0; kt < 4; ++kt) {
                a0 = __builtin_amdgcn_mfma_f32_16x16x32_bf16(A[0][kt], Bf[kt], a0, 0, 0, 0);
                a1 = __builtin_amdgcn_mfma_f32_16x16x32_bf16(A[1][kt], Bf[kt], a1, 0, 0, 0);
            }
            w0 = a0 * ey0;               // rows 32w+4quad+r
            w1 = a1 * ey1;               // rows 32w+16+4quad+r

            if (t && (t & 3) == 0) {     // consume partials written at t-1
                f32x4 ws = *(const f32x4*)wsumS;
                float S = (ws.x + ws.y) + (ws.z + ws.w);
                float rinv = __builtin_amdgcn_rcpf(S);
                c_acc += __logf(S);
                w0 *= rinv; w1 *= rinv;
            }
            if ((t & 3) == 3) {          // publish partial sums (off critical path)
                f32x4 sv = w0 + w1;
                float s = (sv.x + sv.y) + (sv.z + sv.w);
                s += __shfl_xor(s, 16);
                s += __shfl_xor(s, 32);
                if (lane == 0) wsumS[w] = s;
            }

            if (ci == 0) {               // 8 x 8B writes per wave
                uint2 d0 = make_uint2(pkbf16(w0.x, w0.y), pkbf16(w0.z, w0.w));
                uint2 d1 = make_uint2(pkbf16(w1.x, w1.y), pkbf16(w1.z, w1.w));
                *(uint2*)&vS[cur ^ 1][32 * w + 4 * quad]      = d0;
                *(uint2*)&vS[cur ^ 1][32 * w + 16 + 4 * quad] = d1;
            }
            __syncthreads();
            cur ^= 1;
        }
    }

    // out[b] = c_acc + log(sum of stored v) ; lane holds its wave's 8 rows
    f32x4 sv = w0 + w1;
    float s = (sv.x + sv.y) + (sv.z + sv.w);
    s += __shfl_xor(s, 16);
    s += __shfl_xor(s, 32);
    if (lane == 0) redS[w] = s;
    __syncthreads();
    if (tid == 0) {
        f32x4 r = *(const f32x4*)redS;
        out[b] = c_acc + __logf((r.x + r.y) + (r.z + r.w));
    }
}

extern "C" void kernel_launch(void* const* d_in, const int* in_sizes, int n_in,
                              void* d_out, int out_size, void* d_ws, size_t ws_size,
                              hipStream_t stream) {
    const float* y     = (const float*)d_in[0];   // (B, T, K) fp32
    const float* mask  = (const float*)d_in[1];   // (B, T)    fp32 0/1
    const float* trans = (const float*)d_in[2];   // (K, K)    fp32
    float* out = (float*)d_out;                    // (B,)      fp32
    crf_fwd_kernel<<<B_, 256, 0, stream>>>(y, mask, trans, out);
}